// Round 10
// baseline (686.100 us; speedup 1.0000x reference)
//
#include <hip/hip_runtime.h>
#include <math.h>

// ---- problem constants ----
#define N_NODES 33
#define SEQ 24
#define BATCH 64
#define G_GRAPHS (BATCH * SEQ)          // 1536
#define EPG 64
#define E_EDGES (G_GRAPHS * EPG)        // 98304
#define N_TOTAL (G_GRAPHS * N_NODES)    // 50688
#define HID 64
#define HEADS 8
#define HC (HID * HEADS)                // 512
#define LSTM1_H 128
#define LSTM2_H 64
#define NEG_SLOPE 0.2f

__device__ __forceinline__ float sigmoidf_(float x) { return 1.f / (1.f + expf(-x)); }
__device__ __forceinline__ float eluf_(float x) { return x > 0.f ? x : expm1f(x); }
__device__ __forceinline__ float lreluf_(float x) { return x > 0.f ? x : NEG_SLOPE * x; }

// bf16 (RNE) pack/unpack on raw shorts
__device__ __forceinline__ short f2bf(float x) {
  unsigned u = __float_as_uint(x);
  unsigned r = (u + 0x7fffu + ((u >> 16) & 1u)) >> 16;
  return (short)r;
}
__device__ __forceinline__ float bf2f(short b) {
  return __uint_as_float(((unsigned)(unsigned short)b) << 16);
}

typedef __attribute__((ext_vector_type(8))) short bf16x8;
typedef __attribute__((ext_vector_type(4))) float f32x4;

__device__ __forceinline__ void gl2lds16(const void* g, void* l) {
  __builtin_amdgcn_global_load_lds(
      (__attribute__((address_space(1))) const unsigned int*)g,
      (__attribute__((address_space(3))) unsigned int*)l, 16, 0, 0);
}

// ============================================================
// GAT layer 1 (round-4 version — conflict-free, verified)
// ============================================================
__global__ __launch_bounds__(256) void gat1_kernel(
    const float* __restrict__ x, const int* __restrict__ src, const int* __restrict__ dst,
    const float* __restrict__ ea, const float* __restrict__ Wl, const float* __restrict__ Wr,
    const float* __restrict__ We, const float* __restrict__ att, const float* __restrict__ bias,
    short* __restrict__ h1hi, short* __restrict__ h1lo, int g0) {
  __shared__ alignas(16) float Wl_s[2 * 512];
  __shared__ alignas(16) float Wr_s[2 * 512];
  __shared__ alignas(16) float We_s[3 * 512];
  __shared__ alignas(16) float att_s[512];
  __shared__ float xs0_s[N_NODES + 1], xs1_s[N_NODES + 1];
  __shared__ float easX[EPG], easY[EPG], easZ[EPG];
  __shared__ float logit_s[HEADS * 65];   // padded stride 65
  __shared__ int sloc[EPG], dloc[EPG], deg[N_NODES], start[N_NODES], fill[N_NODES], elist[EPG];

  const int g = g0 + blockIdx.x, tid = threadIdx.x;
  const int nb = g * N_NODES, eb = g * EPG;
  const int lb = blockIdx.x * N_NODES;

  for (int i = tid; i < 1024; i += 256) { Wl_s[i] = Wl[i]; Wr_s[i] = Wr[i]; }
  for (int i = tid; i < 1536; i += 256) We_s[i] = We[i];
  for (int i = tid; i < 512; i += 256) att_s[i] = att[i];
  if (tid < 2 * N_NODES) {
    float v = x[nb * 2 + tid];
    if (tid & 1) xs1_s[tid >> 1] = v; else xs0_s[tid >> 1] = v;
  }
  if (tid < EPG) {
    easX[tid] = ea[(eb + tid) * 3 + 0];
    easY[tid] = ea[(eb + tid) * 3 + 1];
    easZ[tid] = ea[(eb + tid) * 3 + 2];
    sloc[tid] = src[eb + tid] - nb;
    dloc[tid] = dst[eb + tid] - nb;
  }
  if (tid < N_NODES) { deg[tid] = 0; fill[tid] = 0; }
  __syncthreads();
  if (tid < EPG) atomicAdd(&deg[dloc[tid]], 1);
  __syncthreads();
  if (tid == 0) { int a = 0; for (int n = 0; n < N_NODES; ++n) { start[n] = a; a += deg[n]; } }
  __syncthreads();
  if (tid < EPG) { int d = dloc[tid]; int p = atomicAdd(&fill[d], 1); elist[start[d] + p] = tid; }

  // logits: h = t>>6 (wave-uniform), e = t&63 (= lane). Weight reads broadcast.
  for (int t = tid; t < EPG * HEADS; t += 256) {
    int h = t >> 6, e = t & 63;
    int s = sloc[e], d = dloc[e];
    float xs0 = xs0_s[s], xs1 = xs1_s[s], xd0 = xs0_s[d], xd1 = xs1_s[d];
    float e0 = easX[e], e1 = easY[e], e2 = easZ[e];
    float acc = 0.f;
    int base = h * 64;
    #pragma unroll
    for (int c4 = 0; c4 < 16; ++c4) {
      int j = base + c4 * 4;
      f32x4 wl0 = *(const f32x4*)(Wl_s + j);
      f32x4 wl1 = *(const f32x4*)(Wl_s + 512 + j);
      f32x4 wr0 = *(const f32x4*)(Wr_s + j);
      f32x4 wr1 = *(const f32x4*)(Wr_s + 512 + j);
      f32x4 we0 = *(const f32x4*)(We_s + j);
      f32x4 we1 = *(const f32x4*)(We_s + 512 + j);
      f32x4 we2 = *(const f32x4*)(We_s + 1024 + j);
      f32x4 at  = *(const f32x4*)(att_s + j);
      #pragma unroll
      for (int q = 0; q < 4; ++q) {
        float v = xs0 * wl0[q] + xs1 * wl1[q]
                + xd0 * wr0[q] + xd1 * wr1[q]
                + e0 * we0[q] + e1 * we1[q] + e2 * we2[q];
        acc += lreluf_(v) * at[q];
      }
    }
    logit_s[h * 65 + e] = acc;
  }
  __syncthreads();

  // segment softmax: h = t>>6 (uniform), n = t&63 (lane), skip n>=33
  for (int t = tid; t < HEADS * 64; t += 256) {
    int h = t >> 6, n = t & 63;
    if (n < N_NODES) {
      int s0 = start[n], dn = deg[n];
      float mx = -1e30f;
      for (int i = 0; i < dn; ++i) mx = fmaxf(mx, logit_s[h * 65 + elist[s0 + i]]);
      float den = 0.f;
      for (int i = 0; i < dn; ++i) den += expf(logit_s[h * 65 + elist[s0 + i]] - mx);
      float inv = 1.f / (den + 1e-16f);
      for (int i = 0; i < dn; ++i) {
        int e = elist[s0 + i];
        logit_s[h * 65 + e] = expf(logit_s[h * 65 + e] - mx) * inv;
      }
    }
  }
  __syncthreads();

  // aggregation: task = (n, 8-channel block). n = t>>6 wave-uniform, jb = lane.
  for (int t = tid; t < N_NODES * 64; t += 256) {
    int n = t >> 6, jb = t & 63;
    int j0 = jb * 8, h = jb >> 3;
    f32x4 wa0 = *(const f32x4*)(Wl_s + j0);
    f32x4 wa1 = *(const f32x4*)(Wl_s + j0 + 4);
    f32x4 wb0 = *(const f32x4*)(Wl_s + 512 + j0);
    f32x4 wb1 = *(const f32x4*)(Wl_s + 512 + j0 + 4);
    float acc[8] = {};
    int s0 = start[n], dn = deg[n];
    for (int i = 0; i < dn; ++i) {
      int e = elist[s0 + i]; int s = sloc[e];
      float a = logit_s[h * 65 + e];
      float ax0 = a * xs0_s[s], ax1 = a * xs1_s[s];
      #pragma unroll
      for (int q = 0; q < 4; ++q) {
        acc[q]     += ax0 * wa0[q] + ax1 * wb0[q];
        acc[4 + q] += ax0 * wa1[q] + ax1 * wb1[q];
      }
    }
    f32x4 b0 = *(const f32x4*)(bias + j0);
    f32x4 b1 = *(const f32x4*)(bias + j0 + 4);
    bf16x8 vh, vl;
    #pragma unroll
    for (int cc = 0; cc < 8; ++cc) {
      float bb = (cc < 4) ? b0[cc] : b1[cc - 4];
      float v = eluf_(acc[cc] + bb);
      short hb = f2bf(v);
      vh[cc] = hb;
      vl[cc] = f2bf(v - bf2f(hb));
    }
    size_t o = (size_t)(lb + n) * HC + j0;
    *(bf16x8*)(h1hi + o) = vh;
    *(bf16x8*)(h1lo + o) = vl;
  }
}

// ============================================================
// merged weight conversion: blocks [0, 2048) -> g2 B-matrix transpose+split,
// blocks [2048, 6272) -> l1_Wih elementwise split.
// ============================================================
__global__ __launch_bounds__(256) void conv_all(
    const float* __restrict__ Wl, const float* __restrict__ Wr,
    short* __restrict__ Bhi, short* __restrict__ Blo,
    const float* __restrict__ W1, short* __restrict__ W1hi, short* __restrict__ W1lo) {
  int b = blockIdx.x;
  if (b < 2048) {
    int idx = b * 256 + threadIdx.x;   // n*512 + k
    int n = idx >> 9, k = idx & 511;
    float v = (n < 512) ? Wl[k * 512 + n] : Wr[k * 512 + (n - 512)];
    short hi = f2bf(v);
    Bhi[idx] = hi;
    Blo[idx] = f2bf(v - bf2f(hi));
  } else {
    int idx = (b - 2048) * 256 + threadIdx.x;
    if (idx < 512 * 2112) {
      float v = W1[idx];
      short hi = f2bf(v);
      W1hi[idx] = hi;
      W1lo[idx] = f2bf(v - bf2f(hi));
    }
  }
}

// ============================================================
// split-bf16 MFMA GEMM, templated tile (round-9 verified):
// <4,4,1>: 128x128 tile, BK=32 (chunk gemms); <2,2,2>: 64x64, BK=64 (final).
// XCD-aware 1D grid swizzle (round-8 verified: FETCH 68.8 -> 35.8 MB).
// ROUND-6 LESSON: never stream an MFMA operand global->VGPR.
// ============================================================
template <int WM, int WN, int NP>
__global__ __launch_bounds__(256) void gemm_mfma(
    const short* __restrict__ Ahi, const short* __restrict__ Alo,
    const short* __restrict__ Bhi, const short* __restrict__ Blo,
    float* __restrict__ C, const float* __restrict__ bias1, const float* __restrict__ bias2,
    int M, int N, int K, int strideA, int strideB) {
  constexpr int BM = 32 * WM, BN = 32 * WN;
  __shared__ short lds[(BM + BN) * 32 * NP * 2];
  short* Ah_s = lds;                        // [NP][BM][32]
  short* Al_s = Ah_s + NP * BM * 32;
  short* Bh_s = Al_s + NP * BM * 32;        // [NP][BN][32]
  short* Bl_s = Bh_s + NP * BN * 32;

  const int R = M / BM, NT = N / BN;
  int b = blockIdx.x;
  int xcd = b & 7, q = b >> 3;
  int ct = q % NT, rg = q / NT;
  int r = rg * 8 + xcd;
  if (r >= R) return;

  const int tid = threadIdx.x;
  const int wave = tid >> 6, lane = tid & 63;
  const int wm = wave >> 1, wn = wave & 1;
  const int bm = r * BM, bn = ct * BN;

  const int rA = lane >> 2;          // 0..15
  const int cA = (lane & 3) * 8;     // 16B unit within 32-k panel row

  f32x4 acc[WM][WN];
  #pragma unroll
  for (int tm = 0; tm < WM; ++tm)
    #pragma unroll
    for (int tn = 0; tn < WN; ++tn) acc[tm][tn] = {0.f, 0.f, 0.f, 0.f};

  for (int k0 = 0; k0 < K; k0 += 32 * NP) {
    #pragma unroll
    for (int p = 0; p < NP; ++p) {
      int kk = k0 + p * 32;
      #pragma unroll
      for (int i = 0; i < BM / 64; ++i) {
        int row = i * 64 + wave * 16;
        size_t go = (size_t)(bm + row + rA) * strideA + kk + cA;
        int lo = p * BM * 32 + row * 32;
        gl2lds16(Ahi + go, Ah_s + lo);
        gl2lds16(Alo + go, Al_s + lo);
      }
      #pragma unroll
      for (int i = 0; i < BN / 64; ++i) {
        int row = i * 64 + wave * 16;
        size_t go = (size_t)(bn + row + rA) * strideB + kk + cA;
        int lo = p * BN * 32 + row * 32;
        gl2lds16(Bhi + go, Bh_s + lo);
        gl2lds16(Blo + go, Bl_s + lo);
      }
    }
    __syncthreads();

    const int fr = lane & 15;
    const int fk = (lane >> 4) * 8;
    #pragma unroll
    for (int p = 0; p < NP; ++p) {
      const int pA = p * BM * 32, pB = p * BN * 32;
      bf16x8 a_h[WM], a_l[WM], b_h[WN], b_l[WN];
      #pragma unroll
      for (int tm = 0; tm < WM; ++tm) {
        int rr = (wm * WM + tm) * 16 + fr;
        a_h[tm] = *(const bf16x8*)(Ah_s + pA + rr * 32 + fk);
        a_l[tm] = *(const bf16x8*)(Al_s + pA + rr * 32 + fk);
      }
      #pragma unroll
      for (int tn = 0; tn < WN; ++tn) {
        int rr = (wn * WN + tn) * 16 + fr;
        b_h[tn] = *(const bf16x8*)(Bh_s + pB + rr * 32 + fk);
        b_l[tn] = *(const bf16x8*)(Bl_s + pB + rr * 32 + fk);
      }
      #pragma unroll
      for (int tm = 0; tm < WM; ++tm)
        #pragma unroll
        for (int tn = 0; tn < WN; ++tn) {
          acc[tm][tn] = __builtin_amdgcn_mfma_f32_16x16x32_bf16(a_h[tm], b_h[tn], acc[tm][tn], 0, 0, 0);
          acc[tm][tn] = __builtin_amdgcn_mfma_f32_16x16x32_bf16(a_h[tm], b_l[tn], acc[tm][tn], 0, 0, 0);
          acc[tm][tn] = __builtin_amdgcn_mfma_f32_16x16x32_bf16(a_l[tm], b_h[tn], acc[tm][tn], 0, 0, 0);
        }
    }
    __syncthreads();
  }

  // epilogue: C/D layout col=lane&15, row=(lane>>4)*4+reg  [m89/m91 verified]
  const int col0 = lane & 15, rq = (lane >> 4) * 4;
  #pragma unroll
  for (int tm = 0; tm < WM; ++tm)
    #pragma unroll
    for (int tn = 0; tn < WN; ++tn) {
      int col = bn + (wn * WN + tn) * 16 + col0;
      float badd = 0.f;
      if (bias1) badd += bias1[col];
      if (bias2) badd += bias2[col];
      #pragma unroll
      for (int rr = 0; rr < 4; ++rr) {
        int row = bm + (wm * WM + tm) * 16 + rq + rr;
        C[(size_t)row * N + col] = acc[tm][tn][rr] + badd;
      }
    }
}

// ============================================================
// GAT layer 2 v3: NO xl/xr LDS staging (round-9 counters: 147968 B LDS ->
// 1 block/CU, Occupancy 10%, 104 us — latency-bound). Lanes = channels:
//  logits: one wave per (edge, head); lane c reads xl[s][h*64+c] and
//    xr[d][h*64+c] as coalesced 256B global rows (L2/L3-resident), computes
//    lrelu(.)*att, 6-step __shfl_xor wave reduction.
//  aggregation: one wave per dst node; lane c accumulates coalesced xl rows
//    over (deg x 8 heads), alpha broadcast from LDS.
// LDS ~13 KB -> occupancy VGPR-bound (many blocks/CU).
// ============================================================
__global__ __launch_bounds__(256) void gat2_kernel(
    const float* __restrict__ xlr, const int* __restrict__ src, const int* __restrict__ dst,
    const float* __restrict__ ea, const float* __restrict__ We,
    const float* __restrict__ att, const float* __restrict__ bias,
    short* __restrict__ h2hi, short* __restrict__ h2lo, int g0) {
  __shared__ alignas(16) float We_s[3 * 512];
  __shared__ alignas(16) float att_s[512];
  __shared__ float b_s[HID];
  __shared__ float easX[EPG], easY[EPG], easZ[EPG];
  __shared__ float logit_s[HEADS * 65];
  __shared__ int sloc[EPG], dloc[EPG], deg[N_NODES], start[N_NODES], fill[N_NODES], elist[EPG];

  const int g = g0 + blockIdx.x, tid = threadIdx.x;
  const int nb = g * N_NODES, eb = g * EPG;
  const int lb = blockIdx.x * N_NODES;
  const int wave = tid >> 6, lane = tid & 63;

  for (int i = tid; i < 1536; i += 256) We_s[i] = We[i];
  for (int i = tid; i < 512; i += 256) att_s[i] = att[i];
  if (tid < HID) b_s[tid] = bias[tid];
  if (tid < EPG) {
    easX[tid] = ea[(eb + tid) * 3 + 0];
    easY[tid] = ea[(eb + tid) * 3 + 1];
    easZ[tid] = ea[(eb + tid) * 3 + 2];
    sloc[tid] = src[eb + tid] - nb;
    dloc[tid] = dst[eb + tid] - nb;
  }
  if (tid < N_NODES) { deg[tid] = 0; fill[tid] = 0; }
  __syncthreads();
  if (tid < EPG) atomicAdd(&deg[dloc[tid]], 1);
  __syncthreads();
  if (tid == 0) { int a = 0; for (int n = 0; n < N_NODES; ++n) { start[n] = a; a += deg[n]; } }
  __syncthreads();
  if (tid < EPG) { int d = dloc[tid]; int p = atomicAdd(&fill[d], 1); elist[start[d] + p] = tid; }
  __syncthreads();

  // logits: wave-task (e,h), lane = channel within head
  #pragma unroll 2
  for (int t = wave; t < EPG * HEADS; t += 4) {
    int e = t >> 3, h = t & 7;
    int s = sloc[e], d = dloc[e];          // LDS broadcast (wave-uniform addr)
    int j = h * 64 + lane;
    float xlv = xlr[(size_t)(lb + s) * 1024 + j];
    float xrv = xlr[(size_t)(lb + d) * 1024 + 512 + j];
    float em = easX[e] * We_s[j] + easY[e] * We_s[512 + j] + easZ[e] * We_s[1024 + j];
    float v = lreluf_(xlv + xrv + em) * att_s[j];
    #pragma unroll
    for (int off = 32; off; off >>= 1) v += __shfl_xor(v, off, 64);
    if (lane == 0) logit_s[h * 65 + e] = v;
  }
  __syncthreads();

  // softmax: h = t>>6 (uniform), n = t&63 (lane), skip n>=33
  for (int t = tid; t < HEADS * 64; t += 256) {
    int h = t >> 6, n = t & 63;
    if (n < N_NODES) {
      int s0 = start[n], dn = deg[n];
      float mx = -1e30f;
      for (int i = 0; i < dn; ++i) mx = fmaxf(mx, logit_s[h * 65 + elist[s0 + i]]);
      float den = 0.f;
      for (int i = 0; i < dn; ++i) den += expf(logit_s[h * 65 + elist[s0 + i]] - mx);
      float inv = 1.f / (den + 1e-16f);
      for (int i = 0; i < dn; ++i) {
        int e = elist[s0 + i];
        logit_s[h * 65 + e] = expf(logit_s[h * 65 + e] - mx) * inv;
      }
    }
  }
  __syncthreads();

  // aggregation: wave-task n, lane = HID channel; head-mean fused (x0.125)
  for (int n = wave; n < N_NODES; n += 4) {
    float acc = 0.f;
    int s0 = start[n], dn = deg[n];
    for (int i = 0; i < dn; ++i) {
      int e = elist[s0 + i], s = sloc[e];
      const float* row = xlr + (size_t)(lb + s) * 1024 + lane;
      #pragma unroll
      for (int h = 0; h < 8; ++h)
        acc += logit_s[h * 65 + e] * row[h * 64];
    }
    float v = eluf_(acc * 0.125f + b_s[lane]);
    short hb = f2bf(v);
    size_t o = (size_t)(nb + n) * HID + lane;
    h2hi[o] = hb;
    h2lo[o] = f2bf(v - bf2f(hb));
  }
}

// ============================================================
// LSTM1 (round-5 no-spill version) + rest of the chain
// ============================================================
__global__ __launch_bounds__(1024, 4) void lstm1_kernel(
    const float* __restrict__ X, const float* __restrict__ Whh, float* __restrict__ Y) {
  __shared__ float hs[LSTM1_H], cs[LSTM1_H], part[4 * LSTM1_H], gs[4 * LSTM1_H];
  const int tid = threadIdx.x;
  const int j = tid & 511, half = tid >> 9;
  const int b = blockIdx.x;
  float4 w[16];
  const float4* wp = (const float4*)(Whh + (size_t)j * LSTM1_H + half * 64);
  #pragma unroll
  for (int q = 0; q < 16; ++q) w[q] = wp[q];
  if (tid < LSTM1_H) { hs[tid] = 0.f; cs[tid] = 0.f; }
  __syncthreads();
  for (int t = 0; t < SEQ; ++t) {
    const float* hb = hs + half * 64;
    float acc = 0.f;
    #pragma unroll
    for (int q = 0; q < 16; ++q) {
      acc += w[q].x * hb[4 * q] + w[q].y * hb[4 * q + 1]
           + w[q].z * hb[4 * q + 2] + w[q].w * hb[4 * q + 3];
    }
    if (half) part[j] = acc;
    __syncthreads();
    if (!half) gs[j] = acc + part[j] + X[((size_t)b * SEQ + t) * 512 + j];
    __syncthreads();
    if (tid < LSTM1_H) {
      float ig = sigmoidf_(gs[tid]);
      float fg = sigmoidf_(gs[LSTM1_H + tid]);
      float gg = tanhf(gs[2 * LSTM1_H + tid]);
      float og = sigmoidf_(gs[3 * LSTM1_H + tid]);
      float c = fg * cs[tid] + ig * gg;
      cs[tid] = c;
      float h = og * tanhf(c);
      hs[tid] = h;
      Y[((size_t)b * SEQ + t) * LSTM1_H + tid] = h;
    }
    __syncthreads();
  }
}

__global__ __launch_bounds__(256) void x2_kernel(
    const float* __restrict__ Y1, const float* __restrict__ Wih,
    const float* __restrict__ bih, const float* __restrict__ bhh,
    float* __restrict__ X2) {
  __shared__ float ys[LSTM1_H];
  const int g = blockIdx.x, j = threadIdx.x;
  if (j < LSTM1_H) ys[j] = Y1[(size_t)g * LSTM1_H + j];
  __syncthreads();
  const float4* wp = (const float4*)(Wih + (size_t)j * LSTM1_H);
  float acc = bih[j] + bhh[j];
  #pragma unroll
  for (int q = 0; q < 32; ++q) {
    float4 w = wp[q];
    acc += w.x * ys[4 * q] + w.y * ys[4 * q + 1] + w.z * ys[4 * q + 2] + w.w * ys[4 * q + 3];
  }
  X2[(size_t)g * 256 + j] = acc;
}

__global__ __launch_bounds__(256, 2) void lstm2_fc_kernel(
    const float* __restrict__ X, const float* __restrict__ Whh,
    const float* __restrict__ fcW, const float* __restrict__ fcb,
    float* __restrict__ out) {
  __shared__ float hs[LSTM2_H], cs[LSTM2_H], gs[4 * LSTM2_H];
  const int b = blockIdx.x, j = threadIdx.x;
  float4 w[16];
  const float4* wp = (const float4*)(Whh + (size_t)j * LSTM2_H);
  #pragma unroll
  for (int q = 0; q < 16; ++q) w[q] = wp[q];
  if (j < LSTM2_H) { hs[j] = 0.f; cs[j] = 0.f; }
  __syncthreads();
  for (int t = 0; t < SEQ; ++t) {
    float acc = X[((size_t)b * SEQ + t) * 256 + j];
    #pragma unroll
    for (int q = 0; q < 16; ++q) {
      acc += w[q].x * hs[4 * q] + w[q].y * hs[4 * q + 1]
           + w[q].z * hs[4 * q + 2] + w[q].w * hs[4 * q + 3];
    }
    gs[j] = acc;
    __syncthreads();
    if (j < LSTM2_H) {
      float ig = sigmoidf_(gs[j]);
      float fg = sigmoidf_(gs[LSTM2_H + j]);
      float gg = tanhf(gs[2 * LSTM2_H + j]);
      float og = sigmoidf_(gs[3 * LSTM2_H + j]);
      float c = fg * cs[j] + ig * gg;
      cs[j] = c;
      hs[j] = og * tanhf(c);
    }
    __syncthreads();
  }
  if (j < 4) {
    float acc = fcb[j];
    #pragma unroll
    for (int k = 0; k < LSTM2_H; ++k) acc += fcW[j * LSTM2_H + k] * hs[k];
    out[b * 4 + j] = acc;
  }
}

// ============================================================
extern "C" void kernel_launch(void* const* d_in, const int* in_sizes, int n_in,
                              void* d_out, int out_size, void* d_ws, size_t ws_size,
                              hipStream_t stream) {
  const float* x       = (const float*)d_in[0];
  const int*   eidx    = (const int*)d_in[1];
  const float* eattr   = (const float*)d_in[2];
  const float* g1_Wl   = (const float*)d_in[3];
  const float* g1_Wr   = (const float*)d_in[4];
  const float* g1_We   = (const float*)d_in[5];
  const float* g1_att  = (const float*)d_in[6];
  const float* g1_b    = (const float*)d_in[7];
  const float* g2_Wl   = (const float*)d_in[8];
  const float* g2_Wr   = (const float*)d_in[9];
  const float* g2_We   = (const float*)d_in[10];
  const float* g2_att  = (const float*)d_in[11];
  const float* g2_b    = (const float*)d_in[12];
  const float* l1_Wih  = (const float*)d_in[13];
  const float* l1_Whh  = (const float*)d_in[14];
  const float* l1_bih  = (const float*)d_in[15];
  const float* l1_bhh  = (const float*)d_in[16];
  const float* l2_Wih  = (const float*)d_in[17];
  const float* l2_Whh  = (const float*)d_in[18];
  const float* l2_bih  = (const float*)d_in[19];
  const float* l2_bhh  = (const float*)d_in[20];
  const float* fc_W    = (const float*)d_in[21];
  const float* fc_b    = (const float*)d_in[22];
  float* out = (float*)d_out;

  const int* src = eidx;
  const int* dst = eidx + E_EDGES;

  // ---- runtime-adaptive chunking: largest chunk size whose ws layout fits.
  // ws_size is constant across calls -> same branch every call (graph-safe).
  const int cand[5] = {1, 2, 3, 4, 6};
  int nchunks = 0;
  short *h1hi = nullptr, *h1lo = nullptr, *h2hi = nullptr, *h2lo = nullptr;
  short *B2hi = nullptr, *B2lo = nullptr, *W1hi = nullptr, *W1lo = nullptr;
  float *xlr2c = nullptr, *X1 = nullptr, *Y1 = nullptr, *X2 = nullptr;
  int chunk_g = 0, chunk_n = 0;
  for (int ci = 0; ci < 5; ++ci) {
    int C = cand[ci];
    int CG = G_GRAPHS / C, CN = CG * N_NODES;
    char* p = (char*)d_ws;
    auto alloc = [&](size_t bytes) { char* r = p; p += (bytes + 255) & ~(size_t)255; return r; };
    short* t_h1hi  = (short*)alloc((size_t)CN * HC * 2);
    short* t_h1lo  = (short*)alloc((size_t)CN * HC * 2);
    float* t_xlr2c = (float*)alloc((size_t)CN * 1024 * 4);
    short* t_h2hi  = (short*)alloc((size_t)G_GRAPHS * 2112 * 2);
    short* t_h2lo  = (short*)alloc((size_t)G_GRAPHS * 2112 * 2);
    short* t_B2hi  = (short*)alloc((size_t)1024 * 512 * 2);
    short* t_B2lo  = (short*)alloc((size_t)1024 * 512 * 2);
    short* t_W1hi  = (short*)alloc((size_t)512 * 2112 * 2);
    short* t_W1lo  = (short*)alloc((size_t)512 * 2112 * 2);
    float* t_X1    = (float*)alloc((size_t)G_GRAPHS * 512 * 4);
    float* t_Y1    = (float*)alloc((size_t)G_GRAPHS * LSTM1_H * 4);
    float* t_X2    = (float*)alloc((size_t)G_GRAPHS * 256 * 4);
    if ((size_t)(p - (char*)d_ws) <= ws_size) {
      nchunks = C; chunk_g = CG; chunk_n = CN;
      h1hi = t_h1hi; h1lo = t_h1lo; xlr2c = t_xlr2c;
      h2hi = t_h2hi; h2lo = t_h2lo; B2hi = t_B2hi; B2lo = t_B2lo;
      W1hi = t_W1hi; W1lo = t_W1lo; X1 = t_X1; Y1 = t_Y1; X2 = t_X2;
      break;
    }
  }
  if (nchunks == 0) return;   // guard: zero output instead of memory fault

  conv_all<<<2048 + (512 * 2112 + 255) / 256, 256, 0, stream>>>(
      g2_Wl, g2_Wr, B2hi, B2lo, l1_Wih, W1hi, W1lo);

  for (int c = 0; c < nchunks; ++c) {
    int g0 = c * chunk_g;
    gat1_kernel<<<chunk_g, 256, 0, stream>>>(x, src, dst, eattr, g1_Wl, g1_Wr, g1_We,
                                             g1_att, g1_b, h1hi, h1lo, g0);
    // 128x128 tiles, BK=32, XCD-swizzled 1D grid
    int R = chunk_n / 128, NT = 1024 / 128;
    int gblocks = 8 * ((R + 7) / 8) * NT;
    gemm_mfma<4, 4, 1><<<gblocks, 256, 0, stream>>>(h1hi, h1lo, B2hi, B2lo, xlr2c,
                                                    (const float*)nullptr, (const float*)nullptr,
                                                    chunk_n, 1024, HC, HC, HC);
    gat2_kernel<<<chunk_g, 256, 0, stream>>>(xlr2c, src, dst, eattr, g2_We,
                                             g2_att, g2_b, h2hi, h2lo, g0);
  }

  // X1 = h2 @ l1_Wih^T + biases  (single dispatch, 64x64 tiles, BK=64: 192 blocks)
  {
    int R = G_GRAPHS / 64, NT = 512 / 64;
    int gblocks = 8 * ((R + 7) / 8) * NT;
    gemm_mfma<2, 2, 2><<<gblocks, 256, 0, stream>>>(h2hi, h2lo, W1hi, W1lo, X1,
                                                    l1_bih, l1_bhh,
                                                    G_GRAPHS, 512, N_NODES * HID,
                                                    N_NODES * HID, N_NODES * HID);
  }

  lstm1_kernel<<<BATCH, 1024, 0, stream>>>(X1, l1_Whh, Y1);
  x2_kernel<<<G_GRAPHS, 256, 0, stream>>>(Y1, l2_Wih, l2_bih, l2_bhh, X2);
  lstm2_fc_kernel<<<BATCH, 256, 0, stream>>>(X2, l2_Whh, fc_W, fc_b, out);
}

// Round 11
// 493.985 us; speedup vs baseline: 1.3889x; 1.3889x over previous
//
#include <hip/hip_runtime.h>
#include <math.h>

// ---- problem constants ----
#define N_NODES 33
#define SEQ 24
#define BATCH 64
#define G_GRAPHS (BATCH * SEQ)          // 1536
#define EPG 64
#define E_EDGES (G_GRAPHS * EPG)        // 98304
#define N_TOTAL (G_GRAPHS * N_NODES)    // 50688
#define HID 64
#define HEADS 8
#define HC (HID * HEADS)                // 512
#define LSTM1_H 128
#define LSTM2_H 64
#define NEG_SLOPE 0.2f

__device__ __forceinline__ float sigmoidf_(float x) { return 1.f / (1.f + expf(-x)); }
__device__ __forceinline__ float eluf_(float x) { return x > 0.f ? x : expm1f(x); }
__device__ __forceinline__ float lreluf_(float x) { return x > 0.f ? x : NEG_SLOPE * x; }

// bf16 (RNE) pack/unpack on raw shorts
__device__ __forceinline__ short f2bf(float x) {
  unsigned u = __float_as_uint(x);
  unsigned r = (u + 0x7fffu + ((u >> 16) & 1u)) >> 16;
  return (short)r;
}
__device__ __forceinline__ float bf2f(short b) {
  return __uint_as_float(((unsigned)(unsigned short)b) << 16);
}

typedef __attribute__((ext_vector_type(8))) short bf16x8;
typedef __attribute__((ext_vector_type(4))) float f32x4;
typedef _Float16 half_t;
typedef __attribute__((ext_vector_type(8))) _Float16 halfx8;

__device__ __forceinline__ void gl2lds16(const void* g, void* l) {
  __builtin_amdgcn_global_load_lds(
      (__attribute__((address_space(1))) const unsigned int*)g,
      (__attribute__((address_space(3))) unsigned int*)l, 16, 0, 0);
}

// ============================================================
// GAT layer 1 (round-4 version — conflict-free, verified)
// ============================================================
__global__ __launch_bounds__(256) void gat1_kernel(
    const float* __restrict__ x, const int* __restrict__ src, const int* __restrict__ dst,
    const float* __restrict__ ea, const float* __restrict__ Wl, const float* __restrict__ Wr,
    const float* __restrict__ We, const float* __restrict__ att, const float* __restrict__ bias,
    short* __restrict__ h1hi, short* __restrict__ h1lo, int g0) {
  __shared__ alignas(16) float Wl_s[2 * 512];
  __shared__ alignas(16) float Wr_s[2 * 512];
  __shared__ alignas(16) float We_s[3 * 512];
  __shared__ alignas(16) float att_s[512];
  __shared__ float xs0_s[N_NODES + 1], xs1_s[N_NODES + 1];
  __shared__ float easX[EPG], easY[EPG], easZ[EPG];
  __shared__ float logit_s[HEADS * 65];   // padded stride 65
  __shared__ int sloc[EPG], dloc[EPG], deg[N_NODES], start[N_NODES], fill[N_NODES], elist[EPG];

  const int g = g0 + blockIdx.x, tid = threadIdx.x;
  const int nb = g * N_NODES, eb = g * EPG;
  const int lb = blockIdx.x * N_NODES;

  for (int i = tid; i < 1024; i += 256) { Wl_s[i] = Wl[i]; Wr_s[i] = Wr[i]; }
  for (int i = tid; i < 1536; i += 256) We_s[i] = We[i];
  for (int i = tid; i < 512; i += 256) att_s[i] = att[i];
  if (tid < 2 * N_NODES) {
    float v = x[nb * 2 + tid];
    if (tid & 1) xs1_s[tid >> 1] = v; else xs0_s[tid >> 1] = v;
  }
  if (tid < EPG) {
    easX[tid] = ea[(eb + tid) * 3 + 0];
    easY[tid] = ea[(eb + tid) * 3 + 1];
    easZ[tid] = ea[(eb + tid) * 3 + 2];
    sloc[tid] = src[eb + tid] - nb;
    dloc[tid] = dst[eb + tid] - nb;
  }
  if (tid < N_NODES) { deg[tid] = 0; fill[tid] = 0; }
  __syncthreads();
  if (tid < EPG) atomicAdd(&deg[dloc[tid]], 1);
  __syncthreads();
  if (tid == 0) { int a = 0; for (int n = 0; n < N_NODES; ++n) { start[n] = a; a += deg[n]; } }
  __syncthreads();
  if (tid < EPG) { int d = dloc[tid]; int p = atomicAdd(&fill[d], 1); elist[start[d] + p] = tid; }

  // logits: h = t>>6 (wave-uniform), e = t&63 (= lane). Weight reads broadcast.
  for (int t = tid; t < EPG * HEADS; t += 256) {
    int h = t >> 6, e = t & 63;
    int s = sloc[e], d = dloc[e];
    float xs0 = xs0_s[s], xs1 = xs1_s[s], xd0 = xs0_s[d], xd1 = xs1_s[d];
    float e0 = easX[e], e1 = easY[e], e2 = easZ[e];
    float acc = 0.f;
    int base = h * 64;
    #pragma unroll
    for (int c4 = 0; c4 < 16; ++c4) {
      int j = base + c4 * 4;
      f32x4 wl0 = *(const f32x4*)(Wl_s + j);
      f32x4 wl1 = *(const f32x4*)(Wl_s + 512 + j);
      f32x4 wr0 = *(const f32x4*)(Wr_s + j);
      f32x4 wr1 = *(const f32x4*)(Wr_s + 512 + j);
      f32x4 we0 = *(const f32x4*)(We_s + j);
      f32x4 we1 = *(const f32x4*)(We_s + 512 + j);
      f32x4 we2 = *(const f32x4*)(We_s + 1024 + j);
      f32x4 at  = *(const f32x4*)(att_s + j);
      #pragma unroll
      for (int q = 0; q < 4; ++q) {
        float v = xs0 * wl0[q] + xs1 * wl1[q]
                + xd0 * wr0[q] + xd1 * wr1[q]
                + e0 * we0[q] + e1 * we1[q] + e2 * we2[q];
        acc += lreluf_(v) * at[q];
      }
    }
    logit_s[h * 65 + e] = acc;
  }
  __syncthreads();

  // segment softmax: h = t>>6 (uniform), n = t&63 (lane), skip n>=33
  for (int t = tid; t < HEADS * 64; t += 256) {
    int h = t >> 6, n = t & 63;
    if (n < N_NODES) {
      int s0 = start[n], dn = deg[n];
      float mx = -1e30f;
      for (int i = 0; i < dn; ++i) mx = fmaxf(mx, logit_s[h * 65 + elist[s0 + i]]);
      float den = 0.f;
      for (int i = 0; i < dn; ++i) den += expf(logit_s[h * 65 + elist[s0 + i]] - mx);
      float inv = 1.f / (den + 1e-16f);
      for (int i = 0; i < dn; ++i) {
        int e = elist[s0 + i];
        logit_s[h * 65 + e] = expf(logit_s[h * 65 + e] - mx) * inv;
      }
    }
  }
  __syncthreads();

  // aggregation: task = (n, 8-channel block). n = t>>6 wave-uniform, jb = lane.
  for (int t = tid; t < N_NODES * 64; t += 256) {
    int n = t >> 6, jb = t & 63;
    int j0 = jb * 8, h = jb >> 3;
    f32x4 wa0 = *(const f32x4*)(Wl_s + j0);
    f32x4 wa1 = *(const f32x4*)(Wl_s + j0 + 4);
    f32x4 wb0 = *(const f32x4*)(Wl_s + 512 + j0);
    f32x4 wb1 = *(const f32x4*)(Wl_s + 512 + j0 + 4);
    float acc[8] = {};
    int s0 = start[n], dn = deg[n];
    for (int i = 0; i < dn; ++i) {
      int e = elist[s0 + i]; int s = sloc[e];
      float a = logit_s[h * 65 + e];
      float ax0 = a * xs0_s[s], ax1 = a * xs1_s[s];
      #pragma unroll
      for (int q = 0; q < 4; ++q) {
        acc[q]     += ax0 * wa0[q] + ax1 * wb0[q];
        acc[4 + q] += ax0 * wa1[q] + ax1 * wb1[q];
      }
    }
    f32x4 b0 = *(const f32x4*)(bias + j0);
    f32x4 b1 = *(const f32x4*)(bias + j0 + 4);
    bf16x8 vh, vl;
    #pragma unroll
    for (int cc = 0; cc < 8; ++cc) {
      float bb = (cc < 4) ? b0[cc] : b1[cc - 4];
      float v = eluf_(acc[cc] + bb);
      short hb = f2bf(v);
      vh[cc] = hb;
      vl[cc] = f2bf(v - bf2f(hb));
    }
    size_t o = (size_t)(lb + n) * HC + j0;
    *(bf16x8*)(h1hi + o) = vh;
    *(bf16x8*)(h1lo + o) = vl;
  }
}

// ============================================================
// merged weight conversion (unchanged)
// ============================================================
__global__ __launch_bounds__(256) void conv_all(
    const float* __restrict__ Wl, const float* __restrict__ Wr,
    short* __restrict__ Bhi, short* __restrict__ Blo,
    const float* __restrict__ W1, short* __restrict__ W1hi, short* __restrict__ W1lo) {
  int b = blockIdx.x;
  if (b < 2048) {
    int idx = b * 256 + threadIdx.x;   // n*512 + k
    int n = idx >> 9, k = idx & 511;
    float v = (n < 512) ? Wl[k * 512 + n] : Wr[k * 512 + (n - 512)];
    short hi = f2bf(v);
    Bhi[idx] = hi;
    Blo[idx] = f2bf(v - bf2f(hi));
  } else {
    int idx = (b - 2048) * 256 + threadIdx.x;
    if (idx < 512 * 2112) {
      float v = W1[idx];
      short hi = f2bf(v);
      W1hi[idx] = hi;
      W1lo[idx] = f2bf(v - bf2f(hi));
    }
  }
}

// ============================================================
// split-bf16 MFMA GEMM, templated tile + output type TC:
// <4,4,1,half_t>: 128x128, BK=32, fp16 C (chunk gemms — halves WRITE traffic)
// <2,2,2,float> : 64x64,  BK=64, fp32 C (final gemm)
// XCD-aware 1D grid swizzle (round-8 verified: FETCH 68.8 -> 35.8 MB).
// ROUND-6 LESSON: never stream an MFMA operand global->VGPR.
// ============================================================
template <int WM, int WN, int NP, typename TC>
__global__ __launch_bounds__(256) void gemm_mfma(
    const short* __restrict__ Ahi, const short* __restrict__ Alo,
    const short* __restrict__ Bhi, const short* __restrict__ Blo,
    TC* __restrict__ C, const float* __restrict__ bias1, const float* __restrict__ bias2,
    int M, int N, int K, int strideA, int strideB) {
  constexpr int BM = 32 * WM, BN = 32 * WN;
  __shared__ short lds[(BM + BN) * 32 * NP * 2];
  short* Ah_s = lds;                        // [NP][BM][32]
  short* Al_s = Ah_s + NP * BM * 32;
  short* Bh_s = Al_s + NP * BM * 32;        // [NP][BN][32]
  short* Bl_s = Bh_s + NP * BN * 32;

  const int R = M / BM, NT = N / BN;
  int b = blockIdx.x;
  int xcd = b & 7, q = b >> 3;
  int ct = q % NT, rg = q / NT;
  int r = rg * 8 + xcd;
  if (r >= R) return;

  const int tid = threadIdx.x;
  const int wave = tid >> 6, lane = tid & 63;
  const int wm = wave >> 1, wn = wave & 1;
  const int bm = r * BM, bn = ct * BN;

  const int rA = lane >> 2;          // 0..15
  const int cA = (lane & 3) * 8;     // 16B unit within 32-k panel row

  f32x4 acc[WM][WN];
  #pragma unroll
  for (int tm = 0; tm < WM; ++tm)
    #pragma unroll
    for (int tn = 0; tn < WN; ++tn) acc[tm][tn] = {0.f, 0.f, 0.f, 0.f};

  for (int k0 = 0; k0 < K; k0 += 32 * NP) {
    #pragma unroll
    for (int p = 0; p < NP; ++p) {
      int kk = k0 + p * 32;
      #pragma unroll
      for (int i = 0; i < BM / 64; ++i) {
        int row = i * 64 + wave * 16;
        size_t go = (size_t)(bm + row + rA) * strideA + kk + cA;
        int lo = p * BM * 32 + row * 32;
        gl2lds16(Ahi + go, Ah_s + lo);
        gl2lds16(Alo + go, Al_s + lo);
      }
      #pragma unroll
      for (int i = 0; i < BN / 64; ++i) {
        int row = i * 64 + wave * 16;
        size_t go = (size_t)(bn + row + rA) * strideB + kk + cA;
        int lo = p * BN * 32 + row * 32;
        gl2lds16(Bhi + go, Bh_s + lo);
        gl2lds16(Blo + go, Bl_s + lo);
      }
    }
    __syncthreads();

    const int fr = lane & 15;
    const int fk = (lane >> 4) * 8;
    #pragma unroll
    for (int p = 0; p < NP; ++p) {
      const int pA = p * BM * 32, pB = p * BN * 32;
      bf16x8 a_h[WM], a_l[WM], b_h[WN], b_l[WN];
      #pragma unroll
      for (int tm = 0; tm < WM; ++tm) {
        int rr = (wm * WM + tm) * 16 + fr;
        a_h[tm] = *(const bf16x8*)(Ah_s + pA + rr * 32 + fk);
        a_l[tm] = *(const bf16x8*)(Al_s + pA + rr * 32 + fk);
      }
      #pragma unroll
      for (int tn = 0; tn < WN; ++tn) {
        int rr = (wn * WN + tn) * 16 + fr;
        b_h[tn] = *(const bf16x8*)(Bh_s + pB + rr * 32 + fk);
        b_l[tn] = *(const bf16x8*)(Bl_s + pB + rr * 32 + fk);
      }
      #pragma unroll
      for (int tm = 0; tm < WM; ++tm)
        #pragma unroll
        for (int tn = 0; tn < WN; ++tn) {
          acc[tm][tn] = __builtin_amdgcn_mfma_f32_16x16x32_bf16(a_h[tm], b_h[tn], acc[tm][tn], 0, 0, 0);
          acc[tm][tn] = __builtin_amdgcn_mfma_f32_16x16x32_bf16(a_h[tm], b_l[tn], acc[tm][tn], 0, 0, 0);
          acc[tm][tn] = __builtin_amdgcn_mfma_f32_16x16x32_bf16(a_l[tm], b_h[tn], acc[tm][tn], 0, 0, 0);
        }
    }
    __syncthreads();
  }

  // epilogue: C/D layout col=lane&15, row=(lane>>4)*4+reg  [m89/m91 verified]
  const int col0 = lane & 15, rq = (lane >> 4) * 4;
  #pragma unroll
  for (int tm = 0; tm < WM; ++tm)
    #pragma unroll
    for (int tn = 0; tn < WN; ++tn) {
      int col = bn + (wn * WN + tn) * 16 + col0;
      float badd = 0.f;
      if (bias1) badd += bias1[col];
      if (bias2) badd += bias2[col];
      #pragma unroll
      for (int rr = 0; rr < 4; ++rr) {
        int row = bm + (wm * WM + tm) * 16 + rq + rr;
        C[(size_t)row * N + col] = (TC)(acc[tm][tn][rr] + badd);
      }
    }
}

// ============================================================
// GAT layer 2 v4: xlr is fp16 (halves the 414 MB round-trip that round-10
// counters exposed: gemm WRITE 101 MB + gat2 FETCH 90.9 MB per chunk).
//  logits: one wave per EDGE; lane covers 8 contiguous channels via one
//    halfx8 (16B) load per operand -> full 1KB/wave coalescing; per-lane
//    We/att hoisted to registers (lane-constant); 3-step segmented
//    shfl_xor reduce per 8-lane head group -> 8 logits/edge/wave.
//  aggregation: one wave per dst node, lane = HID channel (v3 scheme).
// ============================================================
__global__ __launch_bounds__(256) void gat2_kernel(
    const half_t* __restrict__ xlr, const int* __restrict__ src, const int* __restrict__ dst,
    const float* __restrict__ ea, const float* __restrict__ We,
    const float* __restrict__ att, const float* __restrict__ bias,
    short* __restrict__ h2hi, short* __restrict__ h2lo, int g0) {
  __shared__ alignas(16) float We_s[3 * 512];
  __shared__ alignas(16) float att_s[512];
  __shared__ float b_s[HID];
  __shared__ float easX[EPG], easY[EPG], easZ[EPG];
  __shared__ float logit_s[HEADS * 65];
  __shared__ int sloc[EPG], dloc[EPG], deg[N_NODES], start[N_NODES], fill[N_NODES], elist[EPG];

  const int g = g0 + blockIdx.x, tid = threadIdx.x;
  const int nb = g * N_NODES, eb = g * EPG;
  const int lb = blockIdx.x * N_NODES;
  const int wave = tid >> 6, lane = tid & 63;

  for (int i = tid; i < 1536; i += 256) We_s[i] = We[i];
  for (int i = tid; i < 512; i += 256) att_s[i] = att[i];
  if (tid < HID) b_s[tid] = bias[tid];
  if (tid < EPG) {
    easX[tid] = ea[(eb + tid) * 3 + 0];
    easY[tid] = ea[(eb + tid) * 3 + 1];
    easZ[tid] = ea[(eb + tid) * 3 + 2];
    sloc[tid] = src[eb + tid] - nb;
    dloc[tid] = dst[eb + tid] - nb;
  }
  if (tid < N_NODES) { deg[tid] = 0; fill[tid] = 0; }
  __syncthreads();
  if (tid < EPG) atomicAdd(&deg[dloc[tid]], 1);
  __syncthreads();
  if (tid == 0) { int a = 0; for (int n = 0; n < N_NODES; ++n) { start[n] = a; a += deg[n]; } }
  __syncthreads();
  if (tid < EPG) { int d = dloc[tid]; int p = atomicAdd(&fill[d], 1); elist[start[d] + p] = tid; }
  __syncthreads();

  // hoist per-lane weights into registers (channels j0 = lane*8 .. +7)
  const int j0 = lane * 8;
  float w0[8], w1[8], w2[8], at8[8];
  #pragma unroll
  for (int q = 0; q < 8; ++q) {
    w0[q] = We_s[j0 + q];
    w1[q] = We_s[512 + j0 + q];
    w2[q] = We_s[1024 + j0 + q];
    at8[q] = att_s[j0 + q];
  }

  // logits: one wave per edge; lane -> 8 channels; head = lane>>3
  for (int e = wave; e < EPG; e += 4) {
    int s = sloc[e], d = dloc[e];          // wave-uniform LDS broadcast
    halfx8 xlv = *((const halfx8*)(xlr + (size_t)(lb + s) * 1024) + lane);
    halfx8 xrv = *((const halfx8*)(xlr + (size_t)(lb + d) * 1024 + 512) + lane);
    float e0 = easX[e], e1 = easY[e], e2 = easZ[e];
    float acc = 0.f;
    #pragma unroll
    for (int q = 0; q < 8; ++q) {
      float v = (float)xlv[q] + (float)xrv[q] + e0 * w0[q] + e1 * w1[q] + e2 * w2[q];
      acc += lreluf_(v) * at8[q];
    }
    acc += __shfl_xor(acc, 1, 64);
    acc += __shfl_xor(acc, 2, 64);
    acc += __shfl_xor(acc, 4, 64);
    if ((lane & 7) == 0) logit_s[(lane >> 3) * 65 + e] = acc;
  }
  __syncthreads();

  // softmax: h = t>>6 (uniform), n = t&63 (lane), skip n>=33
  for (int t = tid; t < HEADS * 64; t += 256) {
    int h = t >> 6, n = t & 63;
    if (n < N_NODES) {
      int s0 = start[n], dn = deg[n];
      float mx = -1e30f;
      for (int i = 0; i < dn; ++i) mx = fmaxf(mx, logit_s[h * 65 + elist[s0 + i]]);
      float den = 0.f;
      for (int i = 0; i < dn; ++i) den += expf(logit_s[h * 65 + elist[s0 + i]] - mx);
      float inv = 1.f / (den + 1e-16f);
      for (int i = 0; i < dn; ++i) {
        int e = elist[s0 + i];
        logit_s[h * 65 + e] = expf(logit_s[h * 65 + e] - mx) * inv;
      }
    }
  }
  __syncthreads();

  // aggregation: wave-task n, lane = HID channel; head-mean fused (x0.125)
  for (int n = wave; n < N_NODES; n += 4) {
    float acc = 0.f;
    int s0 = start[n], dn = deg[n];
    for (int i = 0; i < dn; ++i) {
      int e = elist[s0 + i], s = sloc[e];
      const half_t* row = xlr + (size_t)(lb + s) * 1024 + lane;
      #pragma unroll
      for (int h = 0; h < 8; ++h)
        acc += logit_s[h * 65 + e] * (float)row[h * 64];
    }
    float v = eluf_(acc * 0.125f + b_s[lane]);
    short hb = f2bf(v);
    size_t o = (size_t)(nb + n) * HID + lane;
    h2hi[o] = hb;
    h2lo[o] = f2bf(v - bf2f(hb));
  }
}

// ============================================================
// LSTM1 (round-5 no-spill version) + rest of the chain
// ============================================================
__global__ __launch_bounds__(1024, 4) void lstm1_kernel(
    const float* __restrict__ X, const float* __restrict__ Whh, float* __restrict__ Y) {
  __shared__ float hs[LSTM1_H], cs[LSTM1_H], part[4 * LSTM1_H], gs[4 * LSTM1_H];
  const int tid = threadIdx.x;
  const int j = tid & 511, half = tid >> 9;
  const int b = blockIdx.x;
  float4 w[16];
  const float4* wp = (const float4*)(Whh + (size_t)j * LSTM1_H + half * 64);
  #pragma unroll
  for (int q = 0; q < 16; ++q) w[q] = wp[q];
  if (tid < LSTM1_H) { hs[tid] = 0.f; cs[tid] = 0.f; }
  __syncthreads();
  for (int t = 0; t < SEQ; ++t) {
    const float* hb = hs + half * 64;
    float acc = 0.f;
    #pragma unroll
    for (int q = 0; q < 16; ++q) {
      acc += w[q].x * hb[4 * q] + w[q].y * hb[4 * q + 1]
           + w[q].z * hb[4 * q + 2] + w[q].w * hb[4 * q + 3];
    }
    if (half) part[j] = acc;
    __syncthreads();
    if (!half) gs[j] = acc + part[j] + X[((size_t)b * SEQ + t) * 512 + j];
    __syncthreads();
    if (tid < LSTM1_H) {
      float ig = sigmoidf_(gs[tid]);
      float fg = sigmoidf_(gs[LSTM1_H + tid]);
      float gg = tanhf(gs[2 * LSTM1_H + tid]);
      float og = sigmoidf_(gs[3 * LSTM1_H + tid]);
      float c = fg * cs[tid] + ig * gg;
      cs[tid] = c;
      float h = og * tanhf(c);
      hs[tid] = h;
      Y[((size_t)b * SEQ + t) * LSTM1_H + tid] = h;
    }
    __syncthreads();
  }
}

__global__ __launch_bounds__(256) void x2_kernel(
    const float* __restrict__ Y1, const float* __restrict__ Wih,
    const float* __restrict__ bih, const float* __restrict__ bhh,
    float* __restrict__ X2) {
  __shared__ float ys[LSTM1_H];
  const int g = blockIdx.x, j = threadIdx.x;
  if (j < LSTM1_H) ys[j] = Y1[(size_t)g * LSTM1_H + j];
  __syncthreads();
  const float4* wp = (const float4*)(Wih + (size_t)j * LSTM1_H);
  float acc = bih[j] + bhh[j];
  #pragma unroll
  for (int q = 0; q < 32; ++q) {
    float4 w = wp[q];
    acc += w.x * ys[4 * q] + w.y * ys[4 * q + 1] + w.z * ys[4 * q + 2] + w.w * ys[4 * q + 3];
  }
  X2[(size_t)g * 256 + j] = acc;
}

__global__ __launch_bounds__(256, 2) void lstm2_fc_kernel(
    const float* __restrict__ X, const float* __restrict__ Whh,
    const float* __restrict__ fcW, const float* __restrict__ fcb,
    float* __restrict__ out) {
  __shared__ float hs[LSTM2_H], cs[LSTM2_H], gs[4 * LSTM2_H];
  const int b = blockIdx.x, j = threadIdx.x;
  float4 w[16];
  const float4* wp = (const float4*)(Whh + (size_t)j * LSTM2_H);
  #pragma unroll
  for (int q = 0; q < 16; ++q) w[q] = wp[q];
  if (j < LSTM2_H) { hs[j] = 0.f; cs[j] = 0.f; }
  __syncthreads();
  for (int t = 0; t < SEQ; ++t) {
    float acc = X[((size_t)b * SEQ + t) * 256 + j];
    #pragma unroll
    for (int q = 0; q < 16; ++q) {
      acc += w[q].x * hs[4 * q] + w[q].y * hs[4 * q + 1]
           + w[q].z * hs[4 * q + 2] + w[q].w * hs[4 * q + 3];
    }
    gs[j] = acc;
    __syncthreads();
    if (j < LSTM2_H) {
      float ig = sigmoidf_(gs[j]);
      float fg = sigmoidf_(gs[LSTM2_H + j]);
      float gg = tanhf(gs[2 * LSTM2_H + j]);
      float og = sigmoidf_(gs[3 * LSTM2_H + j]);
      float c = fg * cs[j] + ig * gg;
      cs[j] = c;
      hs[j] = og * tanhf(c);
    }
    __syncthreads();
  }
  if (j < 4) {
    float acc = fcb[j];
    #pragma unroll
    for (int k = 0; k < LSTM2_H; ++k) acc += fcW[j * LSTM2_H + k] * hs[k];
    out[b * 4 + j] = acc;
  }
}

// ============================================================
extern "C" void kernel_launch(void* const* d_in, const int* in_sizes, int n_in,
                              void* d_out, int out_size, void* d_ws, size_t ws_size,
                              hipStream_t stream) {
  const float* x       = (const float*)d_in[0];
  const int*   eidx    = (const int*)d_in[1];
  const float* eattr   = (const float*)d_in[2];
  const float* g1_Wl   = (const float*)d_in[3];
  const float* g1_Wr   = (const float*)d_in[4];
  const float* g1_We   = (const float*)d_in[5];
  const float* g1_att  = (const float*)d_in[6];
  const float* g1_b    = (const float*)d_in[7];
  const float* g2_Wl   = (const float*)d_in[8];
  const float* g2_Wr   = (const float*)d_in[9];
  const float* g2_We   = (const float*)d_in[10];
  const float* g2_att  = (const float*)d_in[11];
  const float* g2_b    = (const float*)d_in[12];
  const float* l1_Wih  = (const float*)d_in[13];
  const float* l1_Whh  = (const float*)d_in[14];
  const float* l1_bih  = (const float*)d_in[15];
  const float* l1_bhh  = (const float*)d_in[16];
  const float* l2_Wih  = (const float*)d_in[17];
  const float* l2_Whh  = (const float*)d_in[18];
  const float* l2_bih  = (const float*)d_in[19];
  const float* l2_bhh  = (const float*)d_in[20];
  const float* fc_W    = (const float*)d_in[21];
  const float* fc_b    = (const float*)d_in[22];
  float* out = (float*)d_out;

  const int* src = eidx;
  const int* dst = eidx + E_EDGES;

  // ---- runtime-adaptive chunking: largest chunk size whose ws layout fits.
  const int cand[5] = {1, 2, 3, 4, 6};
  int nchunks = 0;
  short *h1hi = nullptr, *h1lo = nullptr, *h2hi = nullptr, *h2lo = nullptr;
  short *B2hi = nullptr, *B2lo = nullptr, *W1hi = nullptr, *W1lo = nullptr;
  half_t *xlr2c = nullptr;
  float *X1 = nullptr, *Y1 = nullptr, *X2 = nullptr;
  int chunk_g = 0, chunk_n = 0;
  for (int ci = 0; ci < 5; ++ci) {
    int C = cand[ci];
    int CG = G_GRAPHS / C, CN = CG * N_NODES;
    char* p = (char*)d_ws;
    auto alloc = [&](size_t bytes) { char* r = p; p += (bytes + 255) & ~(size_t)255; return r; };
    short*  t_h1hi  = (short*)alloc((size_t)CN * HC * 2);
    short*  t_h1lo  = (short*)alloc((size_t)CN * HC * 2);
    half_t* t_xlr2c = (half_t*)alloc((size_t)CN * 1024 * 2);   // fp16 now
    short*  t_h2hi  = (short*)alloc((size_t)G_GRAPHS * 2112 * 2);
    short*  t_h2lo  = (short*)alloc((size_t)G_GRAPHS * 2112 * 2);
    short*  t_B2hi  = (short*)alloc((size_t)1024 * 512 * 2);
    short*  t_B2lo  = (short*)alloc((size_t)1024 * 512 * 2);
    short*  t_W1hi  = (short*)alloc((size_t)512 * 2112 * 2);
    short*  t_W1lo  = (short*)alloc((size_t)512 * 2112 * 2);
    float*  t_X1    = (float*)alloc((size_t)G_GRAPHS * 512 * 4);
    float*  t_Y1    = (float*)alloc((size_t)G_GRAPHS * LSTM1_H * 4);
    float*  t_X2    = (float*)alloc((size_t)G_GRAPHS * 256 * 4);
    if ((size_t)(p - (char*)d_ws) <= ws_size) {
      nchunks = C; chunk_g = CG; chunk_n = CN;
      h1hi = t_h1hi; h1lo = t_h1lo; xlr2c = t_xlr2c;
      h2hi = t_h2hi; h2lo = t_h2lo; B2hi = t_B2hi; B2lo = t_B2lo;
      W1hi = t_W1hi; W1lo = t_W1lo; X1 = t_X1; Y1 = t_Y1; X2 = t_X2;
      break;
    }
  }
  if (nchunks == 0) return;   // guard: zero output instead of memory fault

  conv_all<<<2048 + (512 * 2112 + 255) / 256, 256, 0, stream>>>(
      g2_Wl, g2_Wr, B2hi, B2lo, l1_Wih, W1hi, W1lo);

  for (int c = 0; c < nchunks; ++c) {
    int g0 = c * chunk_g;
    gat1_kernel<<<chunk_g, 256, 0, stream>>>(x, src, dst, eattr, g1_Wl, g1_Wr, g1_We,
                                             g1_att, g1_b, h1hi, h1lo, g0);
    // 128x128 tiles, BK=32, XCD-swizzled 1D grid, fp16 output
    int R = chunk_n / 128, NT = 1024 / 128;
    int gblocks = 8 * ((R + 7) / 8) * NT;
    gemm_mfma<4, 4, 1, half_t><<<gblocks, 256, 0, stream>>>(
        h1hi, h1lo, B2hi, B2lo, xlr2c,
        (const float*)nullptr, (const float*)nullptr,
        chunk_n, 1024, HC, HC, HC);
    gat2_kernel<<<chunk_g, 256, 0, stream>>>(xlr2c, src, dst, eattr, g2_We,
                                             g2_att, g2_b, h2hi, h2lo, g0);
  }

  // X1 = h2 @ l1_Wih^T + biases  (single dispatch, 64x64 tiles, BK=64)
  {
    int R = G_GRAPHS / 64, NT = 512 / 64;
    int gblocks = 8 * ((R + 7) / 8) * NT;
    gemm_mfma<2, 2, 2, float><<<gblocks, 256, 0, stream>>>(
        h2hi, h2lo, W1hi, W1lo, X1,
        l1_bih, l1_bhh,
        G_GRAPHS, 512, N_NODES * HID, N_NODES * HID, N_NODES * HID);
  }

  lstm1_kernel<<<BATCH, 1024, 0, stream>>>(X1, l1_Whh, Y1);
  x2_kernel<<<G_GRAPHS, 256, 0, stream>>>(Y1, l2_Wih, l2_bih, l2_bhh, X2);
  lstm2_fc_kernel<<<BATCH, 256, 0, stream>>>(X2, l2_Whh, fc_W, fc_b, out);
}

// Round 12
// 394.615 us; speedup vs baseline: 1.7387x; 1.2518x over previous
//
#include <hip/hip_runtime.h>
#include <math.h>

// ---- problem constants ----
#define N_NODES 33
#define SEQ 24
#define BATCH 64
#define G_GRAPHS (BATCH * SEQ)          // 1536
#define EPG 64
#define E_EDGES (G_GRAPHS * EPG)        // 98304
#define N_TOTAL (G_GRAPHS * N_NODES)    // 50688
#define HID 64
#define HEADS 8
#define HC (HID * HEADS)                // 512
#define LSTM1_H 128
#define LSTM2_H 64
#define NEG_SLOPE 0.2f

__device__ __forceinline__ float sigmoidf_(float x) { return 1.f / (1.f + expf(-x)); }
__device__ __forceinline__ float eluf_(float x) { return x > 0.f ? x : expm1f(x); }
__device__ __forceinline__ float lreluf_(float x) { return x > 0.f ? x : NEG_SLOPE * x; }

typedef __attribute__((ext_vector_type(4))) float f32x4;
typedef _Float16 half_t;
typedef __attribute__((ext_vector_type(8))) _Float16 halfx8;

__device__ __forceinline__ void gl2lds16(const void* g, void* l) {
  __builtin_amdgcn_global_load_lds(
      (__attribute__((address_space(1))) const unsigned int*)g,
      (__attribute__((address_space(3))) unsigned int*)l, 16, 0, 0);
}

// ============================================================
// GAT layer 1 (round-4 task maps, verified) -> h1 single fp16.
// Error note: fp16 input rounding to a K=512 random-sign dot keeps
// RELATIVE output error ~2^-12 (signal and error both random-walk as
// sqrt(K)) — measured round-11: fp16 xlr cost only 3.8e-6 end-to-end.
// ============================================================
__global__ __launch_bounds__(256) void gat1_kernel(
    const float* __restrict__ x, const int* __restrict__ src, const int* __restrict__ dst,
    const float* __restrict__ ea, const float* __restrict__ Wl, const float* __restrict__ Wr,
    const float* __restrict__ We, const float* __restrict__ att, const float* __restrict__ bias,
    half_t* __restrict__ h1, int g0) {
  __shared__ alignas(16) float Wl_s[2 * 512];
  __shared__ alignas(16) float Wr_s[2 * 512];
  __shared__ alignas(16) float We_s[3 * 512];
  __shared__ alignas(16) float att_s[512];
  __shared__ float xs0_s[N_NODES + 1], xs1_s[N_NODES + 1];
  __shared__ float easX[EPG], easY[EPG], easZ[EPG];
  __shared__ float logit_s[HEADS * 65];   // padded stride 65
  __shared__ int sloc[EPG], dloc[EPG], deg[N_NODES], start[N_NODES], fill[N_NODES], elist[EPG];

  const int g = g0 + blockIdx.x, tid = threadIdx.x;
  const int nb = g * N_NODES, eb = g * EPG;
  const int lb = blockIdx.x * N_NODES;

  for (int i = tid; i < 1024; i += 256) { Wl_s[i] = Wl[i]; Wr_s[i] = Wr[i]; }
  for (int i = tid; i < 1536; i += 256) We_s[i] = We[i];
  for (int i = tid; i < 512; i += 256) att_s[i] = att[i];
  if (tid < 2 * N_NODES) {
    float v = x[nb * 2 + tid];
    if (tid & 1) xs1_s[tid >> 1] = v; else xs0_s[tid >> 1] = v;
  }
  if (tid < EPG) {
    easX[tid] = ea[(eb + tid) * 3 + 0];
    easY[tid] = ea[(eb + tid) * 3 + 1];
    easZ[tid] = ea[(eb + tid) * 3 + 2];
    sloc[tid] = src[eb + tid] - nb;
    dloc[tid] = dst[eb + tid] - nb;
  }
  if (tid < N_NODES) { deg[tid] = 0; fill[tid] = 0; }
  __syncthreads();
  if (tid < EPG) atomicAdd(&deg[dloc[tid]], 1);
  __syncthreads();
  if (tid == 0) { int a = 0; for (int n = 0; n < N_NODES; ++n) { start[n] = a; a += deg[n]; } }
  __syncthreads();
  if (tid < EPG) { int d = dloc[tid]; int p = atomicAdd(&fill[d], 1); elist[start[d] + p] = tid; }

  // logits: h = t>>6 (wave-uniform), e = t&63 (= lane). Weight reads broadcast.
  for (int t = tid; t < EPG * HEADS; t += 256) {
    int h = t >> 6, e = t & 63;
    int s = sloc[e], d = dloc[e];
    float xs0 = xs0_s[s], xs1 = xs1_s[s], xd0 = xs0_s[d], xd1 = xs1_s[d];
    float e0 = easX[e], e1 = easY[e], e2 = easZ[e];
    float acc = 0.f;
    int base = h * 64;
    #pragma unroll
    for (int c4 = 0; c4 < 16; ++c4) {
      int j = base + c4 * 4;
      f32x4 wl0 = *(const f32x4*)(Wl_s + j);
      f32x4 wl1 = *(const f32x4*)(Wl_s + 512 + j);
      f32x4 wr0 = *(const f32x4*)(Wr_s + j);
      f32x4 wr1 = *(const f32x4*)(Wr_s + 512 + j);
      f32x4 we0 = *(const f32x4*)(We_s + j);
      f32x4 we1 = *(const f32x4*)(We_s + 512 + j);
      f32x4 we2 = *(const f32x4*)(We_s + 1024 + j);
      f32x4 at  = *(const f32x4*)(att_s + j);
      #pragma unroll
      for (int q = 0; q < 4; ++q) {
        float v = xs0 * wl0[q] + xs1 * wl1[q]
                + xd0 * wr0[q] + xd1 * wr1[q]
                + e0 * we0[q] + e1 * we1[q] + e2 * we2[q];
        acc += lreluf_(v) * at[q];
      }
    }
    logit_s[h * 65 + e] = acc;
  }
  __syncthreads();

  // segment softmax: h = t>>6 (uniform), n = t&63 (lane), skip n>=33
  for (int t = tid; t < HEADS * 64; t += 256) {
    int h = t >> 6, n = t & 63;
    if (n < N_NODES) {
      int s0 = start[n], dn = deg[n];
      float mx = -1e30f;
      for (int i = 0; i < dn; ++i) mx = fmaxf(mx, logit_s[h * 65 + elist[s0 + i]]);
      float den = 0.f;
      for (int i = 0; i < dn; ++i) den += expf(logit_s[h * 65 + elist[s0 + i]] - mx);
      float inv = 1.f / (den + 1e-16f);
      for (int i = 0; i < dn; ++i) {
        int e = elist[s0 + i];
        logit_s[h * 65 + e] = expf(logit_s[h * 65 + e] - mx) * inv;
      }
    }
  }
  __syncthreads();

  // aggregation: task = (n, 8-channel block). n = t>>6 wave-uniform, jb = lane.
  for (int t = tid; t < N_NODES * 64; t += 256) {
    int n = t >> 6, jb = t & 63;
    int j0 = jb * 8, h = jb >> 3;
    f32x4 wa0 = *(const f32x4*)(Wl_s + j0);
    f32x4 wa1 = *(const f32x4*)(Wl_s + j0 + 4);
    f32x4 wb0 = *(const f32x4*)(Wl_s + 512 + j0);
    f32x4 wb1 = *(const f32x4*)(Wl_s + 512 + j0 + 4);
    float acc[8] = {};
    int s0 = start[n], dn = deg[n];
    for (int i = 0; i < dn; ++i) {
      int e = elist[s0 + i]; int s = sloc[e];
      float a = logit_s[h * 65 + e];
      float ax0 = a * xs0_s[s], ax1 = a * xs1_s[s];
      #pragma unroll
      for (int q = 0; q < 4; ++q) {
        acc[q]     += ax0 * wa0[q] + ax1 * wb0[q];
        acc[4 + q] += ax0 * wa1[q] + ax1 * wb1[q];
      }
    }
    f32x4 b0 = *(const f32x4*)(bias + j0);
    f32x4 b1 = *(const f32x4*)(bias + j0 + 4);
    halfx8 vh;
    #pragma unroll
    for (int cc = 0; cc < 8; ++cc) {
      float bb = (cc < 4) ? b0[cc] : b1[cc - 4];
      vh[cc] = (half_t)eluf_(acc[cc] + bb);
    }
    *(halfx8*)(h1 + (size_t)(lb + n) * HC + j0) = vh;
  }
}

// ============================================================
// merged weight conversion to fp16: blocks [0,2048) -> g2 [Wl|Wr] transpose,
// blocks [2048,...) -> l1_Wih elementwise.
// ============================================================
__global__ __launch_bounds__(256) void conv_all(
    const float* __restrict__ Wl, const float* __restrict__ Wr,
    half_t* __restrict__ B2, const float* __restrict__ W1, half_t* __restrict__ W1f) {
  int b = blockIdx.x;
  if (b < 2048) {
    int idx = b * 256 + threadIdx.x;   // n*512 + k
    int n = idx >> 9, k = idx & 511;
    float v = (n < 512) ? Wl[k * 512 + n] : Wr[k * 512 + (n - 512)];
    B2[idx] = (half_t)v;
  } else {
    int idx = (b - 2048) * 256 + threadIdx.x;
    if (idx < 512 * 2112) W1f[idx] = (half_t)W1[idx];
  }
}

// ============================================================
// single-term fp16 MFMA GEMM (C = A[M,K] @ B[N,K]^T), templated tile:
//   <4,4,2,half_t>: 128x128, BK=64, 32 MFMA + 8 stage-calls/barrier (chunk)
//   <2,2,2,float> : 64x64,  BK=64 (final, K=2112)
// XCD-aware 1D grid swizzle (round-8 verified). strideA/strideB decouple
// row stride from K. K % (32*NP) == 0.
// ROUND-6 LESSON: never stream an MFMA operand global->VGPR.
// Precision: fp16 inputs, fp32 MFMA accumulate. Relative dot-product error
// ~2^-12 (see gat1 note) — round-12 replaces 3-term split-bf16 (round-11
// measured absmax 3.8e-6, 14x margin) with 1-term fp16.
// ============================================================
template <int WM, int WN, int NP, typename TC>
__global__ __launch_bounds__(256) void gemm_f16(
    const half_t* __restrict__ A, const half_t* __restrict__ B,
    TC* __restrict__ C, const float* __restrict__ bias1, const float* __restrict__ bias2,
    int M, int N, int K, int strideA, int strideB) {
  constexpr int BM = 32 * WM, BN = 32 * WN;
  __shared__ half_t lds[(BM + BN) * 32 * NP];
  half_t* A_s = lds;                        // [NP][BM][32]
  half_t* B_s = A_s + NP * BM * 32;         // [NP][BN][32]

  const int R = M / BM, NT = N / BN;
  int b = blockIdx.x;
  int xcd = b & 7, q = b >> 3;
  int ct = q % NT, rg = q / NT;
  int r = rg * 8 + xcd;
  if (r >= R) return;

  const int tid = threadIdx.x;
  const int wave = tid >> 6, lane = tid & 63;
  const int wm = wave >> 1, wn = wave & 1;
  const int bm = r * BM, bn = ct * BN;

  const int rA = lane >> 2;          // 0..15
  const int cA = (lane & 3) * 8;     // 16B unit within 32-k panel row

  f32x4 acc[WM][WN];
  #pragma unroll
  for (int tm = 0; tm < WM; ++tm)
    #pragma unroll
    for (int tn = 0; tn < WN; ++tn) acc[tm][tn] = {0.f, 0.f, 0.f, 0.f};

  for (int k0 = 0; k0 < K; k0 += 32 * NP) {
    #pragma unroll
    for (int p = 0; p < NP; ++p) {
      int kk = k0 + p * 32;
      #pragma unroll
      for (int i = 0; i < BM / 64; ++i) {
        int row = i * 64 + wave * 16;
        gl2lds16(A + (size_t)(bm + row + rA) * strideA + kk + cA,
                 A_s + p * BM * 32 + row * 32);
      }
      #pragma unroll
      for (int i = 0; i < BN / 64; ++i) {
        int row = i * 64 + wave * 16;
        gl2lds16(B + (size_t)(bn + row + rA) * strideB + kk + cA,
                 B_s + p * BN * 32 + row * 32);
      }
    }
    __syncthreads();

    const int fr = lane & 15;
    const int fk = (lane >> 4) * 8;
    #pragma unroll
    for (int p = 0; p < NP; ++p) {
      const int pA = p * BM * 32, pB = p * BN * 32;
      halfx8 af[WM], bf[WN];
      #pragma unroll
      for (int tm = 0; tm < WM; ++tm) {
        int rr = (wm * WM + tm) * 16 + fr;
        af[tm] = *(const halfx8*)(A_s + pA + rr * 32 + fk);
      }
      #pragma unroll
      for (int tn = 0; tn < WN; ++tn) {
        int rr = (wn * WN + tn) * 16 + fr;
        bf[tn] = *(const halfx8*)(B_s + pB + rr * 32 + fk);
      }
      #pragma unroll
      for (int tm = 0; tm < WM; ++tm)
        #pragma unroll
        for (int tn = 0; tn < WN; ++tn)
          acc[tm][tn] = __builtin_amdgcn_mfma_f32_16x16x32_f16(af[tm], bf[tn], acc[tm][tn], 0, 0, 0);
    }
    __syncthreads();
  }

  // epilogue: C/D layout col=lane&15, row=(lane>>4)*4+reg  [m89/m91 verified]
  const int col0 = lane & 15, rq = (lane >> 4) * 4;
  #pragma unroll
  for (int tm = 0; tm < WM; ++tm)
    #pragma unroll
    for (int tn = 0; tn < WN; ++tn) {
      int col = bn + (wn * WN + tn) * 16 + col0;
      float badd = 0.f;
      if (bias1) badd += bias1[col];
      if (bias2) badd += bias2[col];
      #pragma unroll
      for (int rr = 0; rr < 4; ++rr) {
        int row = bm + (wm * WM + tm) * 16 + rq + rr;
        C[(size_t)row * N + col] = (TC)(acc[tm][tn][rr] + badd);
      }
    }
}

// ============================================================
// GAT layer 2 v4 (round-11 verified) -> h2 single fp16.
// ============================================================
__global__ __launch_bounds__(256) void gat2_kernel(
    const half_t* __restrict__ xlr, const int* __restrict__ src, const int* __restrict__ dst,
    const float* __restrict__ ea, const float* __restrict__ We,
    const float* __restrict__ att, const float* __restrict__ bias,
    half_t* __restrict__ h2, int g0) {
  __shared__ alignas(16) float We_s[3 * 512];
  __shared__ alignas(16) float att_s[512];
  __shared__ float b_s[HID];
  __shared__ float easX[EPG], easY[EPG], easZ[EPG];
  __shared__ float logit_s[HEADS * 65];
  __shared__ int sloc[EPG], dloc[EPG], deg[N_NODES], start[N_NODES], fill[N_NODES], elist[EPG];

  const int g = g0 + blockIdx.x, tid = threadIdx.x;
  const int nb = g * N_NODES, eb = g * EPG;
  const int lb = blockIdx.x * N_NODES;
  const int wave = tid >> 6, lane = tid & 63;

  for (int i = tid; i < 1536; i += 256) We_s[i] = We[i];
  for (int i = tid; i < 512; i += 256) att_s[i] = att[i];
  if (tid < HID) b_s[tid] = bias[tid];
  if (tid < EPG) {
    easX[tid] = ea[(eb + tid) * 3 + 0];
    easY[tid] = ea[(eb + tid) * 3 + 1];
    easZ[tid] = ea[(eb + tid) * 3 + 2];
    sloc[tid] = src[eb + tid] - nb;
    dloc[tid] = dst[eb + tid] - nb;
  }
  if (tid < N_NODES) { deg[tid] = 0; fill[tid] = 0; }
  __syncthreads();
  if (tid < EPG) atomicAdd(&deg[dloc[tid]], 1);
  __syncthreads();
  if (tid == 0) { int a = 0; for (int n = 0; n < N_NODES; ++n) { start[n] = a; a += deg[n]; } }
  __syncthreads();
  if (tid < EPG) { int d = dloc[tid]; int p = atomicAdd(&fill[d], 1); elist[start[d] + p] = tid; }
  __syncthreads();

  // hoist per-lane weights into registers (channels j0 = lane*8 .. +7)
  const int j0 = lane * 8;
  float w0[8], w1[8], w2[8], at8[8];
  #pragma unroll
  for (int q = 0; q < 8; ++q) {
    w0[q] = We_s[j0 + q];
    w1[q] = We_s[512 + j0 + q];
    w2[q] = We_s[1024 + j0 + q];
    at8[q] = att_s[j0 + q];
  }

  // logits: one wave per edge; lane -> 8 channels; head = lane>>3
  for (int e = wave; e < EPG; e += 4) {
    int s = sloc[e], d = dloc[e];          // wave-uniform LDS broadcast
    halfx8 xlv = *((const halfx8*)(xlr + (size_t)(lb + s) * 1024) + lane);
    halfx8 xrv = *((const halfx8*)(xlr + (size_t)(lb + d) * 1024 + 512) + lane);
    float e0 = easX[e], e1 = easY[e], e2 = easZ[e];
    float acc = 0.f;
    #pragma unroll
    for (int q = 0; q < 8; ++q) {
      float v = (float)xlv[q] + (float)xrv[q] + e0 * w0[q] + e1 * w1[q] + e2 * w2[q];
      acc += lreluf_(v) * at8[q];
    }
    acc += __shfl_xor(acc, 1, 64);
    acc += __shfl_xor(acc, 2, 64);
    acc += __shfl_xor(acc, 4, 64);
    if ((lane & 7) == 0) logit_s[(lane >> 3) * 65 + e] = acc;
  }
  __syncthreads();

  // softmax: h = t>>6 (uniform), n = t&63 (lane), skip n>=33
  for (int t = tid; t < HEADS * 64; t += 256) {
    int h = t >> 6, n = t & 63;
    if (n < N_NODES) {
      int s0 = start[n], dn = deg[n];
      float mx = -1e30f;
      for (int i = 0; i < dn; ++i) mx = fmaxf(mx, logit_s[h * 65 + elist[s0 + i]]);
      float den = 0.f;
      for (int i = 0; i < dn; ++i) den += expf(logit_s[h * 65 + elist[s0 + i]] - mx);
      float inv = 1.f / (den + 1e-16f);
      for (int i = 0; i < dn; ++i) {
        int e = elist[s0 + i];
        logit_s[h * 65 + e] = expf(logit_s[h * 65 + e] - mx) * inv;
      }
    }
  }
  __syncthreads();

  // aggregation: wave-task n, lane = HID channel; head-mean fused (x0.125)
  for (int n = wave; n < N_NODES; n += 4) {
    float acc = 0.f;
    int s0 = start[n], dn = deg[n];
    for (int i = 0; i < dn; ++i) {
      int e = elist[s0 + i], s = sloc[e];
      const half_t* row = xlr + (size_t)(lb + s) * 1024 + lane;
      #pragma unroll
      for (int h = 0; h < 8; ++h)
        acc += logit_s[h * 65 + e] * (float)row[h * 64];
    }
    float v = eluf_(acc * 0.125f + b_s[lane]);
    h2[(size_t)(nb + n) * HID + lane] = (half_t)v;
  }
}

// ============================================================
// LSTM1 (round-5 no-spill version) + rest of the chain
// ============================================================
__global__ __launch_bounds__(1024, 4) void lstm1_kernel(
    const float* __restrict__ X, const float* __restrict__ Whh, float* __restrict__ Y) {
  __shared__ float hs[LSTM1_H], cs[LSTM1_H], part[4 * LSTM1_H], gs[4 * LSTM1_H];
  const int tid = threadIdx.x;
  const int j = tid & 511, half = tid >> 9;
  const int b = blockIdx.x;
  float4 w[16];
  const float4* wp = (const float4*)(Whh + (size_t)j * LSTM1_H + half * 64);
  #pragma unroll
  for (int q = 0; q < 16; ++q) w[q] = wp[q];
  if (tid < LSTM1_H) { hs[tid] = 0.f; cs[tid] = 0.f; }
  __syncthreads();
  for (int t = 0; t < SEQ; ++t) {
    const float* hb = hs + half * 64;
    float acc = 0.f;
    #pragma unroll
    for (int q = 0; q < 16; ++q) {
      acc += w[q].x * hb[4 * q] + w[q].y * hb[4 * q + 1]
           + w[q].z * hb[4 * q + 2] + w[q].w * hb[4 * q + 3];
    }
    if (half) part[j] = acc;
    __syncthreads();
    if (!half) gs[j] = acc + part[j] + X[((size_t)b * SEQ + t) * 512 + j];
    __syncthreads();
    if (tid < LSTM1_H) {
      float ig = sigmoidf_(gs[tid]);
      float fg = sigmoidf_(gs[LSTM1_H + tid]);
      float gg = tanhf(gs[2 * LSTM1_H + tid]);
      float og = sigmoidf_(gs[3 * LSTM1_H + tid]);
      float c = fg * cs[tid] + ig * gg;
      cs[tid] = c;
      float h = og * tanhf(c);
      hs[tid] = h;
      Y[((size_t)b * SEQ + t) * LSTM1_H + tid] = h;
    }
    __syncthreads();
  }
}

__global__ __launch_bounds__(256) void x2_kernel(
    const float* __restrict__ Y1, const float* __restrict__ Wih,
    const float* __restrict__ bih, const float* __restrict__ bhh,
    float* __restrict__ X2) {
  __shared__ float ys[LSTM1_H];
  const int g = blockIdx.x, j = threadIdx.x;
  if (j < LSTM1_H) ys[j] = Y1[(size_t)g * LSTM1_H + j];
  __syncthreads();
  const float4* wp = (const float4*)(Wih + (size_t)j * LSTM1_H);
  float acc = bih[j] + bhh[j];
  #pragma unroll
  for (int q = 0; q < 32; ++q) {
    float4 w = wp[q];
    acc += w.x * ys[4 * q] + w.y * ys[4 * q + 1] + w.z * ys[4 * q + 2] + w.w * ys[4 * q + 3];
  }
  X2[(size_t)g * 256 + j] = acc;
}

__global__ __launch_bounds__(256, 2) void lstm2_fc_kernel(
    const float* __restrict__ X, const float* __restrict__ Whh,
    const float* __restrict__ fcW, const float* __restrict__ fcb,
    float* __restrict__ out) {
  __shared__ float hs[LSTM2_H], cs[LSTM2_H], gs[4 * LSTM2_H];
  const int b = blockIdx.x, j = threadIdx.x;
  float4 w[16];
  const float4* wp = (const float4*)(Whh + (size_t)j * LSTM2_H);
  #pragma unroll
  for (int q = 0; q < 16; ++q) w[q] = wp[q];
  if (j < LSTM2_H) { hs[j] = 0.f; cs[j] = 0.f; }
  __syncthreads();
  for (int t = 0; t < SEQ; ++t) {
    float acc = X[((size_t)b * SEQ + t) * 256 + j];
    #pragma unroll
    for (int q = 0; q < 16; ++q) {
      acc += w[q].x * hs[4 * q] + w[q].y * hs[4 * q + 1]
           + w[q].z * hs[4 * q + 2] + w[q].w * hs[4 * q + 3];
    }
    gs[j] = acc;
    __syncthreads();
    if (j < LSTM2_H) {
      float ig = sigmoidf_(gs[j]);
      float fg = sigmoidf_(gs[LSTM2_H + j]);
      float gg = tanhf(gs[2 * LSTM2_H + j]);
      float og = sigmoidf_(gs[3 * LSTM2_H + j]);
      float c = fg * cs[j] + ig * gg;
      cs[j] = c;
      hs[j] = og * tanhf(c);
    }
    __syncthreads();
  }
  if (j < 4) {
    float acc = fcb[j];
    #pragma unroll
    for (int k = 0; k < LSTM2_H; ++k) acc += fcW[j * LSTM2_H + k] * hs[k];
    out[b * 4 + j] = acc;
  }
}

// ============================================================
extern "C" void kernel_launch(void* const* d_in, const int* in_sizes, int n_in,
                              void* d_out, int out_size, void* d_ws, size_t ws_size,
                              hipStream_t stream) {
  const float* x       = (const float*)d_in[0];
  const int*   eidx    = (const int*)d_in[1];
  const float* eattr   = (const float*)d_in[2];
  const float* g1_Wl   = (const float*)d_in[3];
  const float* g1_Wr   = (const float*)d_in[4];
  const float* g1_We   = (const float*)d_in[5];
  const float* g1_att  = (const float*)d_in[6];
  const float* g1_b    = (const float*)d_in[7];
  const float* g2_Wl   = (const float*)d_in[8];
  const float* g2_Wr   = (const float*)d_in[9];
  const float* g2_We   = (const float*)d_in[10];
  const float* g2_att  = (const float*)d_in[11];
  const float* g2_b    = (const float*)d_in[12];
  const float* l1_Wih  = (const float*)d_in[13];
  const float* l1_Whh  = (const float*)d_in[14];
  const float* l1_bih  = (const float*)d_in[15];
  const float* l1_bhh  = (const float*)d_in[16];
  const float* l2_Wih  = (const float*)d_in[17];
  const float* l2_Whh  = (const float*)d_in[18];
  const float* l2_bih  = (const float*)d_in[19];
  const float* l2_bhh  = (const float*)d_in[20];
  const float* fc_W    = (const float*)d_in[21];
  const float* fc_b    = (const float*)d_in[22];
  float* out = (float*)d_out;

  const int* src = eidx;
  const int* dst = eidx + E_EDGES;

  // ---- runtime-adaptive chunking: largest chunk size whose ws layout fits.
  const int cand[5] = {1, 2, 3, 4, 6};
  int nchunks = 0;
  half_t *h1 = nullptr, *xlr2c = nullptr, *h2 = nullptr, *B2 = nullptr, *W1f = nullptr;
  float *X1 = nullptr, *Y1 = nullptr, *X2 = nullptr;
  int chunk_g = 0, chunk_n = 0;
  for (int ci = 0; ci < 5; ++ci) {
    int C = cand[ci];
    int CG = G_GRAPHS / C, CN = CG * N_NODES;
    char* p = (char*)d_ws;
    auto alloc = [&](size_t bytes) { char* r = p; p += (bytes + 255) & ~(size_t)255; return r; };
    half_t* t_h1    = (half_t*)alloc((size_t)CN * HC * 2);        // 52 MB @ C=1
    half_t* t_xlr2c = (half_t*)alloc((size_t)CN * 1024 * 2);      // 104 MB @ C=1
    half_t* t_h2    = (half_t*)alloc((size_t)G_GRAPHS * 2112 * 2);
    half_t* t_B2    = (half_t*)alloc((size_t)1024 * 512 * 2);
    half_t* t_W1f   = (half_t*)alloc((size_t)512 * 2112 * 2);
    float*  t_X1    = (float*)alloc((size_t)G_GRAPHS * 512 * 4);
    float*  t_Y1    = (float*)alloc((size_t)G_GRAPHS * LSTM1_H * 4);
    float*  t_X2    = (float*)alloc((size_t)G_GRAPHS * 256 * 4);
    if ((size_t)(p - (char*)d_ws) <= ws_size) {
      nchunks = C; chunk_g = CG; chunk_n = CN;
      h1 = t_h1; xlr2c = t_xlr2c; h2 = t_h2; B2 = t_B2; W1f = t_W1f;
      X1 = t_X1; Y1 = t_Y1; X2 = t_X2;
      break;
    }
  }
  if (nchunks == 0) return;   // guard: zero output instead of memory fault

  conv_all<<<2048 + (512 * 2112 + 255) / 256, 256, 0, stream>>>(
      g2_Wl, g2_Wr, B2, l1_Wih, W1f);

  for (int c = 0; c < nchunks; ++c) {
    int g0 = c * chunk_g;
    gat1_kernel<<<chunk_g, 256, 0, stream>>>(x, src, dst, eattr, g1_Wl, g1_Wr, g1_We,
                                             g1_att, g1_b, h1, g0);
    // 128x128 tiles, BK=64, fp16 1-term, XCD-swizzled 1D grid
    int R = chunk_n / 128, NT = 1024 / 128;
    int gblocks = 8 * ((R + 7) / 8) * NT;
    gemm_f16<4, 4, 2, half_t><<<gblocks, 256, 0, stream>>>(
        h1, B2, xlr2c,
        (const float*)nullptr, (const float*)nullptr,
        chunk_n, 1024, HC, HC, HC);
    gat2_kernel<<<chunk_g, 256, 0, stream>>>(xlr2c, src, dst, eattr, g2_We,
                                             g2_att, g2_b, h2, g0);
  }

  // X1 = h2 @ l1_Wih^T + biases  (single dispatch, 64x64 tiles, BK=64)
  {
    int R = G_GRAPHS / 64, NT = 512 / 64;
    int gblocks = 8 * ((R + 7) / 8) * NT;
    gemm_f16<2, 2, 2, float><<<gblocks, 256, 0, stream>>>(
        h2, W1f, X1,
        l1_bih, l1_bhh,
        G_GRAPHS, 512, N_NODES * HID, N_NODES * HID, N_NODES * HID);
  }

  lstm1_kernel<<<BATCH, 1024, 0, stream>>>(X1, l1_Whh, Y1);
  x2_kernel<<<G_GRAPHS, 256, 0, stream>>>(Y1, l2_Wih, l2_bih, l2_bhh, X2);
  lstm2_fc_kernel<<<BATCH, 256, 0, stream>>>(X2, l2_Whh, fc_W, fc_b, out);
}